// Round 13
// baseline (183.797 us; speedup 1.0000x reference)
//
#include <hip/hip_runtime.h>
#include <stdint.h>
#include <stddef.h>

#define N_SENT 100000
#define N_TYPE 10000
#define NEDGE  640000
#define NROWS  (N_SENT + N_TYPE)
#define MAXDEG 256    // LDS cache per wave; Poisson(64): P(deg>256) ~ 0. Fallback exists.
#define HB     256    // histogram chunks; 256 * 2500 == NEDGE exactly
#define HCHUNK (NEDGE / HB)   // 2500
#define NBUCK  4              // source buckets; bucket = blockIdx&3, XCD = blockIdx%8
#define BROWS  (N_SENT / NBUCK)   // 25000 rows/bucket; bf16 slice = 6.4 MB vs 4 MB L2/XCD

__device__ __forceinline__ float bf2f(uint32_t lo16) {
    return __builtin_bit_cast(float, lo16 << 16);
}
__device__ __forceinline__ uint32_t f2bf(float f) {
    uint32_t u = __builtin_bit_cast(uint32_t, f);
    return (u + 0x7fffu + ((u >> 16) & 1u)) >> 16;
}
// Monotone float<->uint encoding for atomicMax on signed floats.
__device__ __forceinline__ uint32_t encf(float f) {
    uint32_t u = __builtin_bit_cast(uint32_t, f);
    return (u >> 31) ? ~u : (u | 0x80000000u);
}
__device__ __forceinline__ float decf(uint32_t k) {
    uint32_t u = (k >> 31) ? (k & 0x7fffffffu) : ~k;
    return __builtin_bit_cast(float, u);
}

// Inline per-wave dtype probe: bf16 pairs have bf16-sane exponents in the low halfword.
__device__ __forceinline__ bool detect_bf16(const uint32_t* __restrict__ h) {
    uint32_t u = h[threadIdx.x & 63];
    uint32_t e_lo = (u >> 7) & 0xffu;
    int ok = (e_lo >= 100u && e_lo <= 140u) ? 1 : 0;
    unsigned long long m = __ballot(ok);
    return __popcll(m) >= 48;
}

// ---- scores: streaming matvec + global-max of s_src (encoded atomicMax, 1/block) ----
#define SC_BLOCKS 6875   // 6875*256 = 1,760,000 = NROWS*16 (bf16 chunks) = (NROWS*32)/2 (f32)

__global__ __launch_bounds__(256) void scores_k(const void* __restrict__ h_sent,
                                                const void* __restrict__ h_type,
                                                const void* __restrict__ attn_w,
                                                float* __restrict__ s_src,
                                                float* __restrict__ s_dst,
                                                uint32_t* __restrict__ gmax) {
    __shared__ float wmax[4];
    int t    = blockIdx.x * 256 + (int)threadIdx.x;
    int lane = threadIdx.x & 63;
    bool isbf = detect_bf16((const uint32_t*)h_sent);
    if (isbf) {
        uint4 wsv = ((const uint4*)attn_w)[lane & 15];
        uint4 wtv = ((const uint4*)attn_w)[16 + (lane & 15)];
        bool isSrc = t < N_SENT * 16;
        const uint4* p = isSrc ? (const uint4*)h_sent + t
                               : (const uint4*)h_type + (t - N_SENT * 16);
        uint4 h = *p;
        uint4 wv = isSrc ? wsv : wtv;
        float s = bf2f(h.x & 0xffffu) * bf2f(wv.x & 0xffffu)
                + bf2f(h.x >> 16)     * bf2f(wv.x >> 16)
                + bf2f(h.y & 0xffffu) * bf2f(wv.y & 0xffffu)
                + bf2f(h.y >> 16)     * bf2f(wv.y >> 16)
                + bf2f(h.z & 0xffffu) * bf2f(wv.z & 0xffffu)
                + bf2f(h.z >> 16)     * bf2f(wv.z >> 16)
                + bf2f(h.w & 0xffffu) * bf2f(wv.w & 0xffffu)
                + bf2f(h.w >> 16)     * bf2f(wv.w >> 16);
        s += __shfl_xor(s, 1, 64);
        s += __shfl_xor(s, 2, 64);
        s += __shfl_xor(s, 4, 64);
        s += __shfl_xor(s, 8, 64);   // all 16 lanes of the group hold the row score
        if ((lane & 15) == 0) {
            int row = t >> 4;
            if (row < N_SENT) s_src[row] = s;
            else              s_dst[row - N_SENT] = s;
        }
        // block-level max over s_src rows only -> 1 atomic per block
        float z = isSrc ? s : -INFINITY;
        z = fmaxf(z, __shfl_xor(z, 16, 64));
        z = fmaxf(z, __shfl_xor(z, 32, 64));
        if (lane == 0) wmax[threadIdx.x >> 6] = z;
        __syncthreads();
        if (threadIdx.x == 0) {
            float bm = fmaxf(fmaxf(wmax[0], wmax[1]), fmaxf(wmax[2], wmax[3]));
            if (bm > -INFINITY) atomicMax(gmax, encf(bm));
        }
    } else {
        float4 wsv = ((const float4*)attn_w)[lane & 31];
        float4 wtv = ((const float4*)attn_w)[32 + (lane & 31)];
        const int HALF = NROWS * 16;
        int it0 = t, it1 = t + HALF;
        bool s0 = it0 < N_SENT * 32, s1 = it1 < N_SENT * 32;
        const float4* p0 = s0 ? (const float4*)h_sent + it0
                              : (const float4*)h_type + (it0 - N_SENT * 32);
        const float4* p1 = s1 ? (const float4*)h_sent + it1
                              : (const float4*)h_type + (it1 - N_SENT * 32);
        float4 h0 = *p0;
        float4 h1 = *p1;
        __builtin_amdgcn_sched_barrier(0);
        float4 w0 = s0 ? wsv : wtv, w1 = s1 ? wsv : wtv;
        float a = h0.x * w0.x + h0.y * w0.y + h0.z * w0.z + h0.w * w0.w;
        float b = h1.x * w1.x + h1.y * w1.y + h1.z * w1.z + h1.w * w1.w;
        a += __shfl_xor(a, 1, 64);  b += __shfl_xor(b, 1, 64);
        a += __shfl_xor(a, 2, 64);  b += __shfl_xor(b, 2, 64);
        a += __shfl_xor(a, 4, 64);  b += __shfl_xor(b, 4, 64);
        a += __shfl_xor(a, 8, 64);  b += __shfl_xor(b, 8, 64);
        a += __shfl_xor(a, 16, 64); b += __shfl_xor(b, 16, 64);
        if ((lane & 31) == 0) {
            int r0 = it0 >> 5, r1 = it1 >> 5;
            if (r0 < N_SENT) s_src[r0] = a; else s_dst[r0 - N_SENT] = a;
            if (r1 < N_SENT) s_src[r1] = b; else s_dst[r1 - N_SENT] = b;
        }
        // f32 path doesn't use the partitioned agg -> no gmax needed
    }
}

// ---- count: 256 blocks x 2500-edge chunk ----
__global__ __launch_bounds__(256) void count_k(const int* __restrict__ dst,
                                               uint32_t* __restrict__ count2) {
    __shared__ uint32_t hist[N_TYPE];   // 40 KB
    int cb = blockIdx.x;
    int t  = threadIdx.x;
#pragma unroll
    for (int i = 0; i < 40; i++) {
        int idx = i * 256 + t;
        if (idx < N_TYPE) hist[idx] = 0u;
    }
    __syncthreads();
    int e0 = cb * HCHUNK;
    int dv[10];
#pragma unroll
    for (int k = 0; k < 10; k++) {
        int i = k * 256 + t;
        dv[k] = dst[e0 + (i < HCHUNK ? i : HCHUNK - 1)];
    }
    __builtin_amdgcn_sched_barrier(0);
#pragma unroll
    for (int k = 0; k < 10; k++) {
        int i = k * 256 + t;
        if (i < HCHUNK) atomicAdd(&hist[dv[k]], 1u);
    }
    __syncthreads();
    uint4* row = (uint4*)(count2 + (size_t)cb * N_TYPE);
#pragma unroll
    for (int i = 0; i < 10; i++) {
        int idx = i * 256 + t;
        if (idx < N_TYPE / 4) row[idx] = ((const uint4*)hist)[idx];
    }
}

// ---- column exclusive-scan, 8-way parallel ----
__global__ __launch_bounds__(256) void sumscan_k(uint32_t* __restrict__ count2,
                                                 uint32_t* __restrict__ total) {
    int tid  = blockIdx.x * 256 + (int)threadIdx.x;
    int lane = threadIdx.x & 63;
    int bin  = tid >> 3;
    int sub  = tid & 7;
    if (bin >= N_TYPE) return;
    uint32_t vals[32];
#pragma unroll
    for (int c = 0; c < 32; c++)
        vals[c] = count2[(size_t)(sub * 32 + c) * N_TYPE + bin];
    __builtin_amdgcn_sched_barrier(0);
    uint32_t lsum = 0;
#pragma unroll
    for (int c = 0; c < 32; c++) lsum += vals[c];
    uint32_t incl = lsum;
#pragma unroll
    for (int off = 1; off < 8; off <<= 1) {
        uint32_t v = __shfl_up(incl, off, 64);
        if ((lane & 7) >= off) incl += v;
    }
    uint32_t run = incl - lsum;
#pragma unroll
    for (int c = 0; c < 32; c++) {
        uint32_t v = vals[c];
        count2[(size_t)(sub * 32 + c) * N_TYPE + bin] = run;
        run += v;
    }
    if (sub == 7) total[bin] = incl;
}

// ---- single-block exclusive scan of totals -> offsets[N_TYPE+1] ----
__global__ __launch_bounds__(1024) void scan_k(const uint32_t* __restrict__ total,
                                               uint32_t* __restrict__ offsets) {
    const int CH = 10;
    int t = threadIdx.x, lane = t & 63, wv = t >> 6;
    int base = t * CH;
    uint32_t local[CH];
    uint32_t tsum = 0;
#pragma unroll
    for (int i = 0; i < CH; i++) {
        int idx = base + i;
        uint32_t c = (idx < N_TYPE) ? total[idx] : 0u;
        local[i] = c;
        tsum += c;
    }
    uint32_t orig = tsum;
#pragma unroll
    for (int off = 1; off < 64; off <<= 1) {
        uint32_t v = __shfl_up(tsum, off, 64);
        if (lane >= off) tsum += v;
    }
    __shared__ uint32_t wsum[16];
    if (lane == 63) wsum[wv] = tsum;
    __syncthreads();
    if (wv == 0 && lane < 16) {
        uint32_t u = wsum[lane], o = u;
#pragma unroll
        for (int off = 1; off < 16; off <<= 1) {
            uint32_t v = __shfl_up(u, off, 64);
            if (lane >= off) u += v;
        }
        wsum[lane] = u - o;
    }
    __syncthreads();
    uint32_t run = wsum[wv] + tsum - orig;
#pragma unroll
    for (int i = 0; i < CH; i++) {
        int idx = base + i;
        if (idx < N_TYPE) {
            offsets[idx] = run;
            run += local[i];
        } else if (idx == N_TYPE) {
            offsets[idx] = run;
        }
    }
}

// ---- fill: 256 blocks; LDS cursors; LDS-atomic scatter ----
__global__ __launch_bounds__(256) void fill_k(const int* __restrict__ src,
                                              const int* __restrict__ dst,
                                              const uint32_t* __restrict__ offsets,
                                              const uint32_t* __restrict__ base2,
                                              uint32_t* __restrict__ edge_src) {
    __shared__ uint32_t cur[N_TYPE];
    int cb = blockIdx.x;
    int t  = threadIdx.x;
    const uint32_t* brow = base2 + (size_t)cb * N_TYPE;
#pragma unroll
    for (int i = 0; i < 10; i++) {
        int idx = i * 256 + t;
        if (idx < N_TYPE / 4) {
            uint4 o = ((const uint4*)offsets)[idx];
            uint4 b = ((const uint4*)brow)[idx];
            uint4 c; c.x = o.x + b.x; c.y = o.y + b.y; c.z = o.z + b.z; c.w = o.w + b.w;
            ((uint4*)cur)[idx] = c;
        }
    }
    __syncthreads();
    int e0 = cb * HCHUNK;
    int dv[10], sv[10];
#pragma unroll
    for (int k = 0; k < 10; k++) {
        int i = k * 256 + t;
        int e = e0 + (i < HCHUNK ? i : HCHUNK - 1);
        dv[k] = dst[e];
        sv[k] = src[e];
    }
    __builtin_amdgcn_sched_barrier(0);
#pragma unroll
    for (int k = 0; k < 10; k++) {
        int i = k * 256 + t;
        if (i < HCHUNK) {
            uint32_t pos = atomicAdd(&cur[dv[k]], 1u);
            edge_src[pos] = (uint32_t)sv[k];
        }
    }
}

// ==== partitioned agg, bf16 only, zero-metadata design ====
// bucket = blockIdx&3; dispatch round-robins XCDs so XCD p serves only bucket p&3 ->
// its 6.4 MB h_sent slice is ~L2-resident (vs 0% today at the L3 3.3 TB/s ceiling).
// Shared softmax bound m_j = lr(gmax_src + s_dst[j]) (monotone lr => valid upper bound)
// -> no per-bucket max. Denom accumulated via 40K global f32 atomicAdds into dsum.
// Partial vectors: unnormalized bf16 pairs (rel err 2^-9 in a convex combo).
__global__ __launch_bounds__(256) void pagg_k(const void* __restrict__ h_sent,
                                              const float* __restrict__ s_src,
                                              const float* __restrict__ s_dst,
                                              const uint32_t* __restrict__ gmax,
                                              const uint32_t* __restrict__ offsets,
                                              const uint32_t* __restrict__ edge_src,
                                              float* __restrict__ dsum,
                                              uint32_t* __restrict__ part_v) {
    bool isbf = detect_bf16((const uint32_t*)h_sent);
    if (!isbf) return;
    __shared__ float    sc[4][MAXDEG];
    __shared__ uint32_t ss[4][MAXDEG];
    uint32_t p     = blockIdx.x & 3;                       // bucket
    int      wslot = threadIdx.x >> 6;
    int      lane  = threadIdx.x & 63;
    int      j     = (int)(blockIdx.x >> 2) * 4 + wslot;   // grid = 2500*4 -> j < 10000
    uint32_t beg = offsets[j];
    uint32_t deg = offsets[j + 1] - beg;
    float    sdj = s_dst[j];
    float    eb  = decf(*gmax) + sdj;                      // upper bound on raw score
    float    mj  = eb > 0.0f ? eb : 0.01f * eb;            // lr is monotone -> bound on v
    float*    mysc = sc[wslot];
    uint32_t* myss = ss[wslot];
    uint32_t pidx = (uint32_t)j * NBUCK + p;
    uint32_t cnt = 0;
    bool fits = deg <= MAXDEG;
    float denom = 0.0f, a0 = 0.0f, a1 = 0.0f;
    const uint32_t* hp = (const uint32_t*)h_sent;
    if (fits) {
        // compact in-bucket edges into LDS (ballot prefix)
        for (uint32_t k0 = 0; k0 < deg; k0 += 64) {
            uint32_t k = k0 + (uint32_t)lane;
            bool act = k < deg;
            uint32_t s = 0; float v = 0.0f; bool inb = false;
            if (act) {
                s = edge_src[beg + k];
                inb = (s / BROWS) == p;
                if (inb) {
                    v = s_src[s] + sdj;
                    v = v > 0.0f ? v : 0.01f * v;
                }
            }
            unsigned long long msk = __ballot(inb ? 1 : 0);
            uint32_t pos = cnt + (uint32_t)__popcll(msk & ((1ull << lane) - 1ull));
            if (inb) { mysc[pos] = v; myss[pos] = s; }
            cnt += (uint32_t)__popcll(msk);
        }
        uint32_t k = 0;
        for (; k + 8 <= cnt; k += 8) {
            uint32_t sv[8]; float vv[8]; uint32_t gv[8];
#pragma unroll
            for (int i = 0; i < 8; i++) { sv[i] = myss[k + i]; vv[i] = mysc[k + i]; }
#pragma unroll
            for (int i = 0; i < 8; i++) gv[i] = hp[(size_t)sv[i] * 64 + lane];
#pragma unroll
            for (int i = 0; i < 8; i++) {
                float w = __expf(vv[i] - mj);
                denom += w;
                a0 += w * bf2f(gv[i] & 0xffffu);
                a1 += w * bf2f(gv[i] >> 16);
            }
        }
        for (; k < cnt; ++k) {
            float w = __expf(mysc[k] - mj);
            uint32_t g = hp[(size_t)myss[k] * 64 + lane];
            denom += w;
            a0 += w * bf2f(g & 0xffffu);
            a1 += w * bf2f(g >> 16);
        }
    } else {
        for (uint32_t k = 0; k < deg; ++k) {       // wave-uniform serial, filtered
            uint32_t s = edge_src[beg + k];
            if ((s / BROWS) == p) {
                float v = s_src[s] + sdj; v = v > 0.0f ? v : 0.01f * v;
                float w = __expf(v - mj);
                uint32_t g = hp[(size_t)s * 64 + lane];
                denom += w;
                a0 += w * bf2f(g & 0xffffu);
                a1 += w * bf2f(g >> 16);
                cnt++;
            }
        }
    }
    if (lane == 0 && denom > 0.0f) atomicAdd(dsum + j, denom);
    // unnormalized bf16 partial; nontemporal so the partial stream doesn't evict the
    // L2-resident source slice. Zero-store when bucket empty (pcomb reads blindly).
    uint32_t packed = f2bf(a0) | (f2bf(a1) << 16);
    __builtin_nontemporal_store(packed, part_v + (size_t)pidx * 64 + (size_t)lane);
}

// ==== combine partials per dest (bf16 only): plain sum / dsum (shared bound) ====
__global__ __launch_bounds__(256) void pcomb_k(const void* __restrict__ h_sent,
                                               const void* __restrict__ h_type,
                                               const float* __restrict__ dsum,
                                               const uint32_t* __restrict__ part_v,
                                               void* __restrict__ out) {
    bool isbf = detect_bf16((const uint32_t*)h_sent);
    if (!isbf) return;
    int j    = (blockIdx.x * 256 + (int)threadIdx.x) >> 6;
    int lane = threadIdx.x & 63;
    if (j >= N_TYPE) return;
    float D = dsum[j];
    if (!(D > 0.0f)) {   // isolated node keeps its input feature
        ((uint32_t*)out)[(size_t)j * 64 + lane] =
            ((const uint32_t*)h_type)[(size_t)j * 64 + lane];
        return;
    }
    uint32_t gv[NBUCK];
#pragma unroll
    for (int p = 0; p < NBUCK; p++)
        gv[p] = __builtin_nontemporal_load(part_v + ((size_t)(j * NBUCK + p) * 64
                                                     + (size_t)lane));
    float a0 = 0.0f, a1 = 0.0f;
#pragma unroll
    for (int p = 0; p < NBUCK; p++) {
        a0 += bf2f(gv[p] & 0xffffu);
        a1 += bf2f(gv[p] >> 16);
    }
    float inv = 1.0f / D;
    ((uint32_t*)out)[(size_t)j * 64 + lane] = f2bf(a0 * inv) | (f2bf(a1 * inv) << 16);
}

// ---- old agg (round-8 best): f32 path + fallback when workspace too small ----
__global__ __launch_bounds__(256) void agg_k(const void* __restrict__ h_sent,
                                             const void* __restrict__ h_type,
                                             const float* __restrict__ s_src,
                                             const float* __restrict__ s_dst,
                                             const uint32_t* __restrict__ offsets,
                                             const uint32_t* __restrict__ edge_src,
                                             void* __restrict__ out,
                                             int use_part) {
    __shared__ float    sc[4][MAXDEG];
    __shared__ uint32_t ss[4][MAXDEG];
    bool isbf = detect_bf16((const uint32_t*)h_sent);
    if (use_part && isbf) return;        // bf16 handled by pagg+pcomb (uniform exit)
    int j     = (blockIdx.x * 256 + threadIdx.x) >> 6;
    int wslot = threadIdx.x >> 6;
    int lane  = threadIdx.x & 63;
    bool valid = j < N_TYPE;
    uint32_t beg = 0, deg = 0;
    float sdj = 0.0f;
    if (valid) {
        beg = offsets[j];
        deg = offsets[j + 1] - beg;
        sdj = s_dst[j];
    }
    float*    mysc = sc[wslot];
    uint32_t* myss = ss[wslot];
    bool fits = (deg <= MAXDEG);
    float m = -INFINITY;
    for (uint32_t k = lane; k < deg; k += 64) {
        uint32_t s = edge_src[beg + k];
        float v = s_src[s] + sdj;
        v = v > 0.0f ? v : 0.01f * v;
        if (fits) { mysc[k] = v; myss[k] = s; }
        m = fmaxf(m, v);
    }
#pragma unroll
    for (int off = 32; off; off >>= 1) m = fmaxf(m, __shfl_xor(m, off, 64));
    __syncthreads();
    if (!valid) return;
    if (deg == 0) {
        if (isbf) ((uint32_t*)out)[(size_t)j * 64 + lane] =
                      ((const uint32_t*)h_type)[(size_t)j * 64 + lane];
        else      ((float2*)out)[(size_t)j * 64 + lane] =
                      ((const float2*)h_type)[(size_t)j * 64 + lane];
        return;
    }
    float denom = 0.0f, a0 = 0.0f, a1 = 0.0f;
    if (isbf) {
        const uint32_t* hp = (const uint32_t*)h_sent;
        uint32_t k = 0;
        if (fits) {
            for (; k + 16 <= deg; k += 16) {
                uint32_t sv[16]; float vv[16]; uint32_t gv[16];
#pragma unroll
                for (int i = 0; i < 16; i++) { sv[i] = myss[k + i]; vv[i] = mysc[k + i]; }
#pragma unroll
                for (int i = 0; i < 16; i++) gv[i] = hp[(size_t)sv[i] * 64 + lane];
#pragma unroll
                for (int i = 0; i < 16; i++) {
                    float w = __expf(vv[i] - m);
                    denom += w;
                    a0 += w * bf2f(gv[i] & 0xffffu);
                    a1 += w * bf2f(gv[i] >> 16);
                }
            }
            for (; k + 8 <= deg; k += 8) {
                uint32_t sv[8]; float vv[8]; uint32_t gv[8];
#pragma unroll
                for (int i = 0; i < 8; i++) { sv[i] = myss[k + i]; vv[i] = mysc[k + i]; }
#pragma unroll
                for (int i = 0; i < 8; i++) gv[i] = hp[(size_t)sv[i] * 64 + lane];
#pragma unroll
                for (int i = 0; i < 8; i++) {
                    float w = __expf(vv[i] - m);
                    denom += w;
                    a0 += w * bf2f(gv[i] & 0xffffu);
                    a1 += w * bf2f(gv[i] >> 16);
                }
            }
            for (; k < deg; ++k) {
                float w = __expf(mysc[k] - m);
                uint32_t g = hp[(size_t)myss[k] * 64 + lane];
                denom += w;
                a0 += w * bf2f(g & 0xffffu);
                a1 += w * bf2f(g >> 16);
            }
        } else {
            for (k = 0; k < deg; ++k) {
                uint32_t s = edge_src[beg + k];
                float v = s_src[s] + sdj; v = v > 0.0f ? v : 0.01f * v;
                float w = __expf(v - m);
                uint32_t g = hp[(size_t)s * 64 + lane];
                denom += w;
                a0 += w * bf2f(g & 0xffffu);
                a1 += w * bf2f(g >> 16);
            }
        }
        float inv = 1.0f / denom;
        ((uint32_t*)out)[(size_t)j * 64 + lane] = f2bf(a0 * inv) | (f2bf(a1 * inv) << 16);
    } else {
        const float2* hp = (const float2*)h_sent;
        uint32_t k = 0;
        if (fits) {
            for (; k + 16 <= deg; k += 16) {
                uint32_t sv[16]; float vv[16]; float2 gv[16];
#pragma unroll
                for (int i = 0; i < 16; i++) { sv[i] = myss[k + i]; vv[i] = mysc[k + i]; }
#pragma unroll
                for (int i = 0; i < 16; i++) gv[i] = hp[(size_t)sv[i] * 64 + lane];
#pragma unroll
                for (int i = 0; i < 16; i++) {
                    float w = __expf(vv[i] - m);
                    denom += w;
                    a0 += w * gv[i].x;
                    a1 += w * gv[i].y;
                }
            }
            for (; k + 8 <= deg; k += 8) {
                uint32_t sv[8]; float vv[8]; float2 gv[8];
#pragma unroll
                for (int i = 0; i < 8; i++) { sv[i] = myss[k + i]; vv[i] = mysc[k + i]; }
#pragma unroll
                for (int i = 0; i < 8; i++) gv[i] = hp[(size_t)sv[i] * 64 + lane];
#pragma unroll
                for (int i = 0; i < 8; i++) {
                    float w = __expf(vv[i] - m);
                    denom += w;
                    a0 += w * gv[i].x;
                    a1 += w * gv[i].y;
                }
            }
            for (; k < deg; ++k) {
                float w = __expf(mysc[k] - m);
                float2 g = hp[(size_t)myss[k] * 64 + lane];
                denom += w;
                a0 += w * g.x;
                a1 += w * g.y;
            }
        } else {
            for (k = 0; k < deg; ++k) {
                uint32_t s = edge_src[beg + k];
                float v = s_src[s] + sdj; v = v > 0.0f ? v : 0.01f * v;
                float w = __expf(v - m);
                float2 g = hp[(size_t)s * 64 + lane];
                denom += w;
                a0 += w * g.x;
                a1 += w * g.y;
            }
        }
        float inv = 1.0f / denom;
        ((float2*)out)[(size_t)j * 64 + lane] = make_float2(a0 * inv, a1 * inv);
    }
}

static inline size_t align_up(size_t x) { return (x + 255) & ~(size_t)255; }

extern "C" void kernel_launch(void* const* d_in, const int* in_sizes, int n_in,
                              void* d_out, int out_size, void* d_ws, size_t ws_size,
                              hipStream_t stream) {
    const void* h_sent = d_in[0];
    const void* h_type = d_in[1];
    const void* attn_w = d_in[2];
    const int* src_idx = (const int*)d_in[3];
    const int* dst_idx = (const int*)d_in[4];

    // Layout == bit-identical footprint to the round-5 proven-fit (13,320,704 B).
    // gmax lives in s_dst's alignment tail; dsum aliases `total` (dead after scan_k);
    // part_v aliases count2 (dead after fill_k). Sequential stream -> no races.
    char* w = (char*)d_ws;
    float*    s_src     = (float*)w;    w += align_up((size_t)N_SENT * 4);        // 400,128
    float*    s_dst     = (float*)w;    w += align_up((size_t)N_TYPE * 4);        // 40,192
    uint32_t* gmax      = (uint32_t*)((char*)s_dst + (size_t)N_TYPE * 4);         // tail
    uint32_t* total     = (uint32_t*)w; w += align_up((size_t)N_TYPE * 4);        // 40,192
    uint32_t* offsets   = (uint32_t*)w; w += align_up((size_t)(N_TYPE + 1) * 4);  // 40,192
    uint32_t* edge_src  = (uint32_t*)w; w += align_up((size_t)NEDGE * 4);         // 2,560,000
    uint32_t* count2    = (uint32_t*)w;                                           // 10,240,000
    uint32_t* part_v    = (uint32_t*)w;   // alias (N_TYPE*NBUCK*64*4 == HB*N_TYPE*4)
    float*    dsum      = (float*)total;  // alias
    size_t need = (size_t)(w - (char*)d_ws) + (size_t)HB * N_TYPE * 4;  // 13,320,704
    int use_part = (need <= ws_size) ? 1 : 0;

    hipMemsetAsync(gmax, 0, 4, stream);   // enc-space 0 == below all finite floats
    scores_k<<<SC_BLOCKS, 256, 0, stream>>>(h_sent, h_type, attn_w, s_src, s_dst, gmax);
    count_k<<<HB, 256, 0, stream>>>(dst_idx, count2);
    sumscan_k<<<(N_TYPE * 8 + 255) / 256, 256, 0, stream>>>(count2, total);
    scan_k<<<1, 1024, 0, stream>>>(total, offsets);
    fill_k<<<HB, 256, 0, stream>>>(src_idx, dst_idx, offsets, count2, edge_src);
    if (use_part) {
        hipMemsetAsync(dsum, 0, (size_t)N_TYPE * 4, stream);   // total is dead now
        pagg_k<<<(N_TYPE / 4) * NBUCK, 256, 0, stream>>>(h_sent, s_src, s_dst, gmax,
                                                         offsets, edge_src,
                                                         dsum, part_v);
        pcomb_k<<<(N_TYPE + 3) / 4, 256, 0, stream>>>(h_sent, h_type,
                                                      dsum, part_v, d_out);
    }
    agg_k<<<(N_TYPE + 3) / 4, 256, 0, stream>>>(h_sent, h_type, s_src, s_dst,
                                                offsets, edge_src, d_out, use_part);
}